// Round 5
// baseline (235.763 us; speedup 1.0000x reference)
//
#include <hip/hip_runtime.h>

// ReluGalois: y = Horner(coeff, x), degree 8 (9 coefficients), float32 in/out.
// 33,554,432 elements = 8,388,608 float4s (exact, no tail).
// Memory-bound: 8 B/elem traffic, 8 FMA/elem. 4 independent float4 loads in
// flight per thread per iteration (64 B/lane) for deep memory-level
// parallelism; unguarded fast path when the iteration space divides exactly.

#define NCOEF 9

template <bool EXACT>
__global__ __launch_bounds__(256) void relu_galois_poly(
    const float* __restrict__ x,
    const float* __restrict__ coeff,
    float* __restrict__ out,
    int n4)  // number of float4 elements
{
    float c[NCOEF];
#pragma unroll
    for (int i = 0; i < NCOEF; ++i) c[i] = coeff[i];

    const float4* __restrict__ xv = reinterpret_cast<const float4*>(x);
    float4* __restrict__       ov = reinterpret_cast<float4*>(out);

    const int tid  = blockIdx.x * blockDim.x + threadIdx.x;
    const int nthr = gridDim.x * blockDim.x;  // 524288 at full grid

    for (int base = tid; base < n4; base += 4 * nthr) {
        const int i0 = base;
        const int i1 = base + nthr;
        const int i2 = base + 2 * nthr;
        const int i3 = base + 3 * nthr;

        float4 v0, v1, v2, v3;
        bool b1 = true, b2 = true, b3 = true;
        if (EXACT) {
            // n4 % (4*nthr) == 0: all four indices in range, no compares.
            v0 = xv[i0]; v1 = xv[i1]; v2 = xv[i2]; v3 = xv[i3];
        } else {
            b1 = i1 < n4; b2 = i2 < n4; b3 = i3 < n4;
            v0 = xv[i0];
            if (b1) v1 = xv[i1];
            if (b2) v2 = xv[i2];
            if (b3) v3 = xv[i3];
        }

        float a0 = c[0], a1 = c[0], a2 = c[0], a3 = c[0];
        float d0 = c[0], d1 = c[0], d2 = c[0], d3 = c[0];
        float e0 = c[0], e1 = c[0], e2 = c[0], e3 = c[0];
        float f0 = c[0], f1 = c[0], f2 = c[0], f3 = c[0];
#pragma unroll
        for (int k = 1; k < NCOEF; ++k) {
            a0 = fmaf(a0, v0.x, c[k]); a1 = fmaf(a1, v0.y, c[k]);
            a2 = fmaf(a2, v0.z, c[k]); a3 = fmaf(a3, v0.w, c[k]);
            d0 = fmaf(d0, v1.x, c[k]); d1 = fmaf(d1, v1.y, c[k]);
            d2 = fmaf(d2, v1.z, c[k]); d3 = fmaf(d3, v1.w, c[k]);
            e0 = fmaf(e0, v2.x, c[k]); e1 = fmaf(e1, v2.y, c[k]);
            e2 = fmaf(e2, v2.z, c[k]); e3 = fmaf(e3, v2.w, c[k]);
            f0 = fmaf(f0, v3.x, c[k]); f1 = fmaf(f1, v3.y, c[k]);
            f2 = fmaf(f2, v3.z, c[k]); f3 = fmaf(f3, v3.w, c[k]);
        }

        ov[i0] = make_float4(a0, a1, a2, a3);
        if (EXACT || b1) ov[i1] = make_float4(d0, d1, d2, d3);
        if (EXACT || b2) ov[i2] = make_float4(e0, e1, e2, e3);
        if (EXACT || b3) ov[i3] = make_float4(f0, f1, f2, f3);
    }
}

extern "C" void kernel_launch(void* const* d_in, const int* in_sizes, int n_in,
                              void* d_out, int out_size, void* d_ws, size_t ws_size,
                              hipStream_t stream) {
    const float* x     = (const float*)d_in[0];
    const float* coeff = (const float*)d_in[1];
    float* out         = (float*)d_out;

    const int n  = in_sizes[0];      // 33,554,432
    const int n4 = n / 4;            // 8,388,608 float4s (exact)

    const int block = 256;
    int grid = (n4 + block - 1) / block;
    if (grid > 2048) grid = 2048;    // 8 blocks/CU, grid-stride

    const int nthr = grid * block;
    if (n4 % (4 * nthr) == 0) {
        relu_galois_poly<true><<<grid, block, 0, stream>>>(x, coeff, out, n4);
    } else {
        relu_galois_poly<false><<<grid, block, 0, stream>>>(x, coeff, out, n4);
    }
}

// Round 7
// 221.198 us; speedup vs baseline: 1.0658x; 1.0658x over previous
//
#include <hip/hip_runtime.h>

// ReluGalois: y = Horner(coeff, x), degree 8 (9 coefficients), float32 in/out.
// 33,554,432 elements = 8,388,608 float4s (exact, no tail).
// R5 counters: 82-84us, 3.05 TB/s effective, VALUBusy 5% -> not compute-bound,
// not over-fetching. Theory: L3 write-allocate thrash (256MB working set ==
// 256MB L3; stores evict L3-resident input). Fix: non-temporal load+store so
// single-use streams bypass L3 allocation. Shape reverted to simple
// grid-stride (R1 shape measured <= 4-deep MLP shape).

#define NCOEF 9

typedef float f32x4 __attribute__((ext_vector_type(4)));

__global__ __launch_bounds__(256) void relu_galois_poly(
    const f32x4* __restrict__ xv,
    const float* __restrict__ coeff,
    f32x4* __restrict__ ov,
    int n4)  // number of float4 elements
{
    // Coefficients: uniform-address scalar loads, hoisted to registers once.
    float c[NCOEF];
#pragma unroll
    for (int i = 0; i < NCOEF; ++i) c[i] = coeff[i];

    const int tid  = blockIdx.x * blockDim.x + threadIdx.x;
    const int nthr = gridDim.x * blockDim.x;

    for (int i = tid; i < n4; i += nthr) {
        // nt load: single-use stream, don't allocate in L3.
        f32x4 v = __builtin_nontemporal_load(xv + i);

        f32x4 a = {c[0], c[0], c[0], c[0]};
#pragma unroll
        for (int k = 1; k < NCOEF; ++k) {
            f32x4 ck = {c[k], c[k], c[k], c[k]};
            a = a * v + ck;  // contracts to v_fma under hipcc default fp-contract
        }

        // nt store: stream to HBM, don't evict input lines from L3.
        __builtin_nontemporal_store(a, ov + i);
    }
}

extern "C" void kernel_launch(void* const* d_in, const int* in_sizes, int n_in,
                              void* d_out, int out_size, void* d_ws, size_t ws_size,
                              hipStream_t stream) {
    const f32x4* x     = (const f32x4*)d_in[0];
    const float* coeff = (const float*)d_in[1];
    f32x4* out         = (f32x4*)d_out;

    const int n  = in_sizes[0];      // 33,554,432
    const int n4 = n / 4;            // 8,388,608 float4s (exact)

    const int block = 256;
    int grid = (n4 + block - 1) / block;
    if (grid > 2048) grid = 2048;    // 8 blocks/CU, 16 float4s/thread

    relu_galois_poly<<<grid, block, 0, stream>>>(x, coeff, out, n4);
}

// Round 10
// 218.802 us; speedup vs baseline: 1.0775x; 1.0109x over previous
//
#include <hip/hip_runtime.h>

// ReluGalois: y = Horner(coeff, x), degree 8 (9 coefficients), float32 in/out.
// 33,554,432 elements = 8,388,608 float4s (exact, no tail).
// R5: 82-84us @ 2048-block grid-stride (3.05 TB/s). R7: +nt load/store ->
// ~68-70us (est. from bench delta; below top-5 cutoff). Still ~55% of the
// 6.3-6.7 TB/s this chip demonstrates on copy/fill. R8 experiment: maximal
// TLP -- full grid, ONE float4 per thread, no loop. Waves hold exactly one
// load+store and retire; the HW dispatcher streams fresh blocks (the shape
// the 6.7 TB/s fill and 6.29 TB/s copy use). nt kept on both sides.

#define NCOEF 9

typedef float f32x4 __attribute__((ext_vector_type(4)));

__global__ __launch_bounds__(256) void relu_galois_poly(
    const f32x4* __restrict__ xv,
    const float* __restrict__ coeff,
    f32x4* __restrict__ ov)
{
    // Coefficients: uniform-address scalar loads -> s_load broadcast.
    float c[NCOEF];
#pragma unroll
    for (int i = 0; i < NCOEF; ++i) c[i] = coeff[i];

    const int i = blockIdx.x * 256 + threadIdx.x;  // grid sized exactly to n4

    f32x4 v = __builtin_nontemporal_load(xv + i);

    f32x4 a = {c[0], c[0], c[0], c[0]};
#pragma unroll
    for (int k = 1; k < NCOEF; ++k) {
        f32x4 ck = {c[k], c[k], c[k], c[k]};
        a = a * v + ck;  // contracts to v_fma
    }

    __builtin_nontemporal_store(a, ov + i);
}

// Fallback for sizes not divisible by (4*256) -- not hit for 8x2048x2048.
__global__ __launch_bounds__(256) void relu_galois_poly_tail(
    const float* __restrict__ x,
    const float* __restrict__ coeff,
    float* __restrict__ out,
    int n, int start)
{
    float c[NCOEF];
#pragma unroll
    for (int i = 0; i < NCOEF; ++i) c[i] = coeff[i];
    int i = start + blockIdx.x * 256 + threadIdx.x;
    if (i < n) {
        float v = x[i];
        float a = c[0];
#pragma unroll
        for (int k = 1; k < NCOEF; ++k) a = fmaf(a, v, c[k]);
        out[i] = a;
    }
}

extern "C" void kernel_launch(void* const* d_in, const int* in_sizes, int n_in,
                              void* d_out, int out_size, void* d_ws, size_t ws_size,
                              hipStream_t stream) {
    const float* x     = (const float*)d_in[0];
    const float* coeff = (const float*)d_in[1];
    float* out         = (float*)d_out;

    const int n  = in_sizes[0];      // 33,554,432
    const int n4 = n / 4;            // 8,388,608 float4s

    const int block = 256;
    const int grid  = n4 / block;    // 32,768 blocks, exact for our shape

    relu_galois_poly<<<grid, block, 0, stream>>>(
        (const f32x4*)x, coeff, (f32x4*)out);

    const int done = grid * block * 4;  // == n for our shape
    if (done < n) {
        const int rem = n - done;
        relu_galois_poly_tail<<<(rem + block - 1) / block, block, 0, stream>>>(
            x, coeff, out, n, done);
    }
}